// Round 6
// baseline (64.115 us; speedup 1.0000x reference)
//
#include <hip/hip_runtime.h>

#define BB 16
#define NN 128
#define DD 128

// Transpose weights into float4-interleaved layout:
// WmT4[((dcol>>2)*128 + k)*4 + (dcol&3)] = Wm[k*384 + dcol]; WuT4 likewise.
__global__ __launch_bounds__(256) void wtrans_kernel(const float* __restrict__ Wm,
                                                     const float* __restrict__ Wu,
                                                     float* __restrict__ WmT4,
                                                     float* __restrict__ WuT4) {
    const int idx = blockIdx.x * 256 + threadIdx.x;
    if (idx < 384 * 128) {
        const int k = idx / 384, dcol = idx % 384;
        WmT4[((dcol >> 2) * 128 + k) * 4 + (dcol & 3)] = Wm[idx];
    } else {
        const int o = idx - 384 * 128;
        const int k = o / 256, dcol = o % 256;
        WuT4[((dcol >> 2) * 128 + k) * 4 + (dcol & 3)] = Wu[o];
    }
}

// Block = (b, 8 j's) as 2 sets of 4. 512 threads: waves 0-3 compute, 4-7 stream.
// Pipeline: [C ∥ S_A] [D_A ∥ S_B1] [E_A ∥ S_B2] [D_B] [E_B].
__global__ __launch_bounds__(512, 2) void mpnn_kernel(
    const float* __restrict__ h, const float* __restrict__ adj,
    const float* __restrict__ e, const float* __restrict__ WmT4,
    const float* __restrict__ bm, const float* __restrict__ WuT4,
    const float* __restrict__ bu, float* __restrict__ out) {
    const int blk = blockIdx.x;
    const int b = blk >> 4;
    const int jbase = (blk & 15) * 8;
    const int t = threadIdx.x;

    __shared__ float adj_s[8][NN];
    __shared__ float h_s[8][DD];
    __shared__ float ah_s[8][DD];
    __shared__ float ms_s[4][DD];
    __shared__ float4 redA[8][32];
    __shared__ float4 redB[8][32];
    __shared__ float deg_s[8];

    // ---- stage adj columns + h rows ----
    for (int x = t; x < 8 * NN; x += 512) {
        const int i = x >> 3, jj = x & 7;
        adj_s[jj][i] = adj[(size_t)(b * NN + i) * NN + jbase + jj];
    }
    for (int x = t; x < 8 * DD; x += 512) {
        const int jj = x >> 7, d0 = x & 127;
        h_s[jj][d0] = h[(size_t)(b * NN + jbase + jj) * DD + d0];
    }
    __syncthreads();                                   // sync0

    const int k = t & 127, jl = (t >> 7) & 1;
    // stream-role state (persists across barriers; only waves 4-7 use it)
    const int g = (t >> 5) & 7;                        // stream group 0..7
    const int jjS = g & 3, ihS = g >> 2, d4 = t & 31;
    const float4* __restrict__ e4A =
        (const float4*)e + ((size_t)(b * NN) * NN + jbase + jjS) * 32 + d4;
    const float4* __restrict__ e4B = e4A + 4 * 32;     // j += 4
    const int i0 = ihS * 64;
    float4 accB = make_float4(0.f, 0.f, 0.f, 0.f);

    if (t < 256) {
        // deg[jj] = sum_i adj[i][jj], jj = t>>5 (8 groups of 32 lanes)
        const int jj = t >> 5, l = t & 31;
        float s = adj_s[jj][l] + adj_s[jj][l + 32] + adj_s[jj][l + 64] + adj_s[jj][l + 96];
        #pragma unroll
        for (int off = 16; off; off >>= 1) s += __shfl_xor(s, off);
        if (l == 0) deg_s[jj] = s;

        // C: ah[j][k] for j = jl, jl+2, jl+4, jl+6
        float a0 = 0.f, a1 = 0.f, a2 = 0.f, a3 = 0.f;
        const float* __restrict__ hp = h + (size_t)b * NN * DD + k;
        #pragma unroll 8
        for (int m = 0; m < 32; ++m) {
            const float4 aA = *(const float4*)&adj_s[jl][4 * m];
            const float4 aB = *(const float4*)&adj_s[jl + 2][4 * m];
            const float4 aC = *(const float4*)&adj_s[jl + 4][4 * m];
            const float4 aD = *(const float4*)&adj_s[jl + 6][4 * m];
            const float h0 = hp[(size_t)(4 * m + 0) * DD];
            const float h1 = hp[(size_t)(4 * m + 1) * DD];
            const float h2 = hp[(size_t)(4 * m + 2) * DD];
            const float h3 = hp[(size_t)(4 * m + 3) * DD];
            a0 += aA.x * h0 + aA.y * h1 + aA.z * h2 + aA.w * h3;
            a1 += aB.x * h0 + aB.y * h1 + aB.z * h2 + aB.w * h3;
            a2 += aC.x * h0 + aC.y * h1 + aC.z * h2 + aC.w * h3;
            a3 += aD.x * h0 + aD.y * h1 + aD.z * h2 + aD.w * h3;
        }
        ah_s[jl][k] = a0; ah_s[jl + 2][k] = a1;
        ah_s[jl + 4][k] = a2; ah_s[jl + 6][k] = a3;
    } else {
        // stream set A: 64 i's per group
        float4 acc = make_float4(0.f, 0.f, 0.f, 0.f);
        #pragma unroll 8
        for (int ii = 0; ii < 64; ++ii) {
            const int i = i0 + ii;
            const float a = adj_s[jjS][i];
            if (a != 0.0f) {
                const float4 v = e4A[(size_t)i * (NN * 32)];
                acc.x += a * v.x; acc.y += a * v.y;
                acc.z += a * v.z; acc.w += a * v.w;
            }
        }
        redA[g][d4] = acc;
    }
    __syncthreads();                                   // sync1

    if (t < 256) {
        // D(A): ms for j = jl, jl+2 (es read directly from redA)
        float pa0 = 0, pa1 = 0, ph0 = 0, ph1 = 0, pe0 = 0, pe1 = 0;
        const float4* __restrict__ w1p = (const float4*)WmT4 + k;
        #pragma unroll 4
        for (int q = 0; q < 32; ++q) {
            const float4 w1 = w1p[q * 128];
            const float4 w2 = w1p[(32 + q) * 128];
            const float4 w3 = w1p[(64 + q) * 128];
            const float4 rA0 = redA[jl][q],     rA1 = redA[jl + 4][q];
            const float4 rB0 = redA[jl + 2][q], rB1 = redA[jl + 6][q];
            const float4 eA = make_float4(rA0.x + rA1.x, rA0.y + rA1.y, rA0.z + rA1.z, rA0.w + rA1.w);
            const float4 eB = make_float4(rB0.x + rB1.x, rB0.y + rB1.y, rB0.z + rB1.z, rB0.w + rB1.w);
            const float4 ahA = *(const float4*)&ah_s[jl][4 * q];
            const float4 ahB = *(const float4*)&ah_s[jl + 2][4 * q];
            const float4 hA  = *(const float4*)&h_s[jl][4 * q];
            const float4 hB  = *(const float4*)&h_s[jl + 2][4 * q];
            pa0 += ahA.x * w1.x + ahA.y * w1.y + ahA.z * w1.z + ahA.w * w1.w;
            pa1 += ahB.x * w1.x + ahB.y * w1.y + ahB.z * w1.z + ahB.w * w1.w;
            ph0 += hA.x * w2.x + hA.y * w2.y + hA.z * w2.z + hA.w * w2.w;
            ph1 += hB.x * w2.x + hB.y * w2.y + hB.z * w2.z + hB.w * w2.w;
            pe0 += eA.x * w3.x + eA.y * w3.y + eA.z * w3.z + eA.w * w3.w;
            pe1 += eB.x * w3.x + eB.y * w3.y + eB.z * w3.z + eB.w * w3.w;
        }
        const float bmk = bm[k];
        ms_s[jl][k]     = pa0 + pe0 + deg_s[jl]     * (ph0 + bmk);
        ms_s[jl + 2][k] = pa1 + pe1 + deg_s[jl + 2] * (ph1 + bmk);
    } else {
        // stream set B, first half
        #pragma unroll 8
        for (int ii = 0; ii < 32; ++ii) {
            const int i = i0 + ii;
            const float a = adj_s[4 + jjS][i];
            if (a != 0.0f) {
                const float4 v = e4B[(size_t)i * (NN * 32)];
                accB.x += a * v.x; accB.y += a * v.y;
                accB.z += a * v.z; accB.w += a * v.w;
            }
        }
    }
    __syncthreads();                                   // sync2

    if (t < 256) {
        // E(A): out rows jbase+jl, jbase+jl+2
        float o0 = 0, o1 = 0;
        const float4* __restrict__ wap = (const float4*)WuT4 + k;
        #pragma unroll 4
        for (int q = 0; q < 32; ++q) {
            const float4 wa = wap[q * 128];
            const float4 wb = wap[(32 + q) * 128];
            const float4 hA = *(const float4*)&h_s[jl][4 * q];
            const float4 hB = *(const float4*)&h_s[jl + 2][4 * q];
            const float4 mA = *(const float4*)&ms_s[jl][4 * q];
            const float4 mB = *(const float4*)&ms_s[jl + 2][4 * q];
            o0 += hA.x * wa.x + hA.y * wa.y + hA.z * wa.z + hA.w * wa.w
                + mA.x * wb.x + mA.y * wb.y + mA.z * wb.z + mA.w * wb.w;
            o1 += hB.x * wa.x + hB.y * wa.y + hB.z * wa.z + hB.w * wa.w
                + mB.x * wb.x + mB.y * wb.y + mB.z * wb.z + mB.w * wb.w;
        }
        const float buk = bu[k];
        out[(size_t)(b * NN + jbase + jl) * DD + k]     = o0 + buk;
        out[(size_t)(b * NN + jbase + jl + 2) * DD + k] = o1 + buk;
    } else {
        // stream set B, second half
        #pragma unroll 8
        for (int ii = 32; ii < 64; ++ii) {
            const int i = i0 + ii;
            const float a = adj_s[4 + jjS][i];
            if (a != 0.0f) {
                const float4 v = e4B[(size_t)i * (NN * 32)];
                accB.x += a * v.x; accB.y += a * v.y;
                accB.z += a * v.z; accB.w += a * v.w;
            }
        }
        redB[g][d4] = accB;
    }
    __syncthreads();                                   // sync3

    if (t < 256) {
        // D(B): ms for j = 4+jl, 4+jl+2
        float pa0 = 0, pa1 = 0, ph0 = 0, ph1 = 0, pe0 = 0, pe1 = 0;
        const float4* __restrict__ w1p = (const float4*)WmT4 + k;
        #pragma unroll 4
        for (int q = 0; q < 32; ++q) {
            const float4 w1 = w1p[q * 128];
            const float4 w2 = w1p[(32 + q) * 128];
            const float4 w3 = w1p[(64 + q) * 128];
            const float4 rA0 = redB[jl][q],     rA1 = redB[jl + 4][q];
            const float4 rB0 = redB[jl + 2][q], rB1 = redB[jl + 6][q];
            const float4 eA = make_float4(rA0.x + rA1.x, rA0.y + rA1.y, rA0.z + rA1.z, rA0.w + rA1.w);
            const float4 eB = make_float4(rB0.x + rB1.x, rB0.y + rB1.y, rB0.z + rB1.z, rB0.w + rB1.w);
            const float4 ahA = *(const float4*)&ah_s[4 + jl][4 * q];
            const float4 ahB = *(const float4*)&ah_s[6 + jl][4 * q];
            const float4 hA  = *(const float4*)&h_s[4 + jl][4 * q];
            const float4 hB  = *(const float4*)&h_s[6 + jl][4 * q];
            pa0 += ahA.x * w1.x + ahA.y * w1.y + ahA.z * w1.z + ahA.w * w1.w;
            pa1 += ahB.x * w1.x + ahB.y * w1.y + ahB.z * w1.z + ahB.w * w1.w;
            ph0 += hA.x * w2.x + hA.y * w2.y + hA.z * w2.z + hA.w * w2.w;
            ph1 += hB.x * w2.x + hB.y * w2.y + hB.z * w2.z + hB.w * w2.w;
            pe0 += eA.x * w3.x + eA.y * w3.y + eA.z * w3.z + eA.w * w3.w;
            pe1 += eB.x * w3.x + eB.y * w3.y + eB.z * w3.z + eB.w * w3.w;
        }
        const float bmk = bm[k];
        ms_s[jl][k]     = pa0 + pe0 + deg_s[4 + jl] * (ph0 + bmk);
        ms_s[jl + 2][k] = pa1 + pe1 + deg_s[6 + jl] * (ph1 + bmk);
    }
    __syncthreads();                                   // sync4

    if (t < 256) {
        // E(B): out rows jbase+4+jl, jbase+4+jl+2
        float o0 = 0, o1 = 0;
        const float4* __restrict__ wap = (const float4*)WuT4 + k;
        #pragma unroll 4
        for (int q = 0; q < 32; ++q) {
            const float4 wa = wap[q * 128];
            const float4 wb = wap[(32 + q) * 128];
            const float4 hA = *(const float4*)&h_s[4 + jl][4 * q];
            const float4 hB = *(const float4*)&h_s[6 + jl][4 * q];
            const float4 mA = *(const float4*)&ms_s[jl][4 * q];
            const float4 mB = *(const float4*)&ms_s[jl + 2][4 * q];
            o0 += hA.x * wa.x + hA.y * wa.y + hA.z * wa.z + hA.w * wa.w
                + mA.x * wb.x + mA.y * wb.y + mA.z * wb.z + mA.w * wb.w;
            o1 += hB.x * wa.x + hB.y * wa.y + hB.z * wa.z + hB.w * wa.w
                + mB.x * wb.x + mB.y * wb.y + mB.z * wb.z + mB.w * wb.w;
        }
        const float buk = bu[k];
        out[(size_t)(b * NN + jbase + 4 + jl) * DD + k]     = o0 + buk;
        out[(size_t)(b * NN + jbase + 6 + jl) * DD + k]     = o1 + buk;
    }
}

extern "C" void kernel_launch(void* const* d_in, const int* in_sizes, int n_in,
                              void* d_out, int out_size, void* d_ws, size_t ws_size,
                              hipStream_t stream) {
    const float* h   = (const float*)d_in[0];
    const float* adj = (const float*)d_in[1];
    const float* e   = (const float*)d_in[2];
    const float* Wm  = (const float*)d_in[3];
    const float* bm  = (const float*)d_in[4];
    const float* Wu  = (const float*)d_in[5];
    const float* bu  = (const float*)d_in[6];
    float* out  = (float*)d_out;
    float* WmT4 = (float*)d_ws;                // 384*128 floats
    float* WuT4 = WmT4 + 384 * 128;            // 256*128 floats (320 KB total)

    wtrans_kernel<<<320, 256, 0, stream>>>(Wm, Wu, WmT4, WuT4);
    mpnn_kernel<<<BB * (NN / 8), 512, 0, stream>>>(h, adj, e, WmT4, bm, WuT4, bu, out);
}

// Round 7
// 45.345 us; speedup vs baseline: 1.4140x; 1.4140x over previous
//
#include <hip/hip_runtime.h>

#define BB 16
#define NN 128
#define DD 128

// K1: es[b,j,d] = sum_i adj[b,i,j]*e[b,i,j,d].  One block per (b,j), 2048 blocks
// -> 8 blocks/CU, 32 waves/CU. Dense branch-free loads (zeros handled by FMA),
// 4 independent loads per unrolled iteration for max loads-in-flight.
// Side job (first 320 blocks): build float4-interleaved weight transposes.
// es aliases d_out (each fuse block later reads only rows it overwrites).
__global__ __launch_bounds__(256) void es_kernel(const float* __restrict__ e,
                                                 const float* __restrict__ adj,
                                                 float* __restrict__ es,
                                                 const float* __restrict__ Wm,
                                                 const float* __restrict__ Wu,
                                                 float* __restrict__ WmT4,
                                                 float* __restrict__ WuT4) {
    const int bj = blockIdx.x;          // b*128 + j
    const int t = threadIdx.x;

    if (bj < 320) {                     // 320*256 = 384*128 + 256*128
        const int idx = bj * 256 + t;
        if (idx < 384 * 128) {
            const int k = idx / 384, dcol = idx % 384;
            WmT4[((dcol >> 2) * 128 + k) * 4 + (dcol & 3)] = Wm[idx];
        } else {
            const int o = idx - 384 * 128;
            const int k = o / 256, dcol = o % 256;
            WuT4[((dcol >> 2) * 128 + k) * 4 + (dcol & 3)] = Wu[o];
        }
    }

    const int b = bj >> 7, j = bj & 127;
    __shared__ float adj_s[NN];
    __shared__ float4 red[8][32];
    if (t < NN) adj_s[t] = adj[(size_t)(b * NN + t) * NN + j];
    __syncthreads();

    const int d4 = t & 31, ig = t >> 5;          // 8 groups x 16 rows
    const float4* __restrict__ e4 =
        (const float4*)e + ((size_t)(b * NN) * NN + j) * 32 + d4;
    const int i0 = ig * 16;
    float4 acc = make_float4(0.f, 0.f, 0.f, 0.f);
    #pragma unroll
    for (int ii = 0; ii < 16; ii += 4) {
        const float4 v0 = e4[(size_t)(i0 + ii + 0) * (NN * 32)];
        const float4 v1 = e4[(size_t)(i0 + ii + 1) * (NN * 32)];
        const float4 v2 = e4[(size_t)(i0 + ii + 2) * (NN * 32)];
        const float4 v3 = e4[(size_t)(i0 + ii + 3) * (NN * 32)];
        const float a0 = adj_s[i0 + ii + 0];
        const float a1 = adj_s[i0 + ii + 1];
        const float a2 = adj_s[i0 + ii + 2];
        const float a3 = adj_s[i0 + ii + 3];
        acc.x += a0 * v0.x; acc.y += a0 * v0.y; acc.z += a0 * v0.z; acc.w += a0 * v0.w;
        acc.x += a1 * v1.x; acc.y += a1 * v1.y; acc.z += a1 * v1.z; acc.w += a1 * v1.w;
        acc.x += a2 * v2.x; acc.y += a2 * v2.y; acc.z += a2 * v2.z; acc.w += a2 * v2.w;
        acc.x += a3 * v3.x; acc.y += a3 * v3.y; acc.z += a3 * v3.z; acc.w += a3 * v3.w;
    }
    red[ig][d4] = acc;
    __syncthreads();
    if (t < 32) {
        float4 s = red[0][t];
        #pragma unroll
        for (int r = 1; r < 8; ++r) {
            const float4 v = red[r][t];
            s.x += v.x; s.y += v.y; s.z += v.z; s.w += v.w;
        }
        ((float4*)es)[(size_t)bj * 32 + t] = s;
    }
}

// K2: fused small GEMMs. Block = (b, 4 j's), 256 threads, 512 blocks
// (2 blocks/CU). Weight reads via WmT4/WuT4: thread k loads 4 consecutive-d
// weights as one float4, coalesced across lanes.
__global__ __launch_bounds__(256) void fuse_kernel(
    const float* __restrict__ h, const float* __restrict__ adj,
    const float* __restrict__ es, const float* __restrict__ WmT4,
    const float* __restrict__ bm, const float* __restrict__ WuT4,
    const float* __restrict__ bu, float* __restrict__ out) {
    const int blk = blockIdx.x;
    const int b = blk >> 5;
    const int jbase = (blk & 31) * 4;
    const int t = threadIdx.x;

    __shared__ float adj_s[4][NN];
    __shared__ float h_s[4][DD];
    __shared__ float es_s[4][DD];
    __shared__ float ah_s[4][DD];
    __shared__ float ms_s[4][DD];
    __shared__ float deg_s[4];

    // stage adj columns (gather, small), h + es rows (coalesced)
    for (int x = t; x < 4 * NN; x += 256) {
        const int i = x >> 2, jj = x & 3;
        adj_s[jj][i] = adj[(size_t)(b * NN + i) * NN + jbase + jj];
    }
    for (int x = t; x < 4 * DD; x += 256) {
        const int jj = x >> 7, d0 = x & 127;
        h_s[jj][d0]  = h [(size_t)(b * NN + jbase + jj) * DD + d0];
        es_s[jj][d0] = es[(size_t)(b * NN + jbase + jj) * DD + d0];
    }
    __syncthreads();

    // deg[jj] = sum_i adj[i][jj]
    if (t < 128) {
        const int jj = t >> 5, l = t & 31;
        float s = adj_s[jj][l] + adj_s[jj][l + 32] + adj_s[jj][l + 64] + adj_s[jj][l + 96];
        #pragma unroll
        for (int off = 16; off; off >>= 1) s += __shfl_xor(s, off);
        if (l == 0) deg_s[jj] = s;
    }

    const int k = t & 127, jl = t >> 7;

    // C: ah[jj][k] = sum_i adj[i][jj]*h[b,i,k]  (h coalesced across lanes)
    {
        float a0 = 0.f, a1 = 0.f;
        const float* __restrict__ hp = h + (size_t)b * NN * DD + k;
        #pragma unroll 8
        for (int m = 0; m < 32; ++m) {
            const float4 aA = *(const float4*)&adj_s[jl][4 * m];
            const float4 aB = *(const float4*)&adj_s[jl + 2][4 * m];
            const float h0 = hp[(size_t)(4 * m + 0) * DD];
            const float h1 = hp[(size_t)(4 * m + 1) * DD];
            const float h2 = hp[(size_t)(4 * m + 2) * DD];
            const float h3 = hp[(size_t)(4 * m + 3) * DD];
            a0 += aA.x * h0 + aA.y * h1 + aA.z * h2 + aA.w * h3;
            a1 += aB.x * h0 + aB.y * h1 + aB.z * h2 + aB.w * h3;
        }
        ah_s[jl][k] = a0;
        ah_s[jl + 2][k] = a1;
    }
    __syncthreads();

    // D: msum[jj][k] for jj = jl, jl+2
    {
        float pa0 = 0, pa1 = 0, ph0 = 0, ph1 = 0, pe0 = 0, pe1 = 0;
        const float4* __restrict__ w1p = (const float4*)WmT4 + k;
        #pragma unroll 4
        for (int q = 0; q < 32; ++q) {
            const float4 w1 = w1p[q * 128];
            const float4 w2 = w1p[(32 + q) * 128];
            const float4 w3 = w1p[(64 + q) * 128];
            const float4 ahA = *(const float4*)&ah_s[jl][4 * q];
            const float4 ahB = *(const float4*)&ah_s[jl + 2][4 * q];
            const float4 hA  = *(const float4*)&h_s[jl][4 * q];
            const float4 hB  = *(const float4*)&h_s[jl + 2][4 * q];
            const float4 eA  = *(const float4*)&es_s[jl][4 * q];
            const float4 eB  = *(const float4*)&es_s[jl + 2][4 * q];
            pa0 += ahA.x * w1.x + ahA.y * w1.y + ahA.z * w1.z + ahA.w * w1.w;
            pa1 += ahB.x * w1.x + ahB.y * w1.y + ahB.z * w1.z + ahB.w * w1.w;
            ph0 += hA.x * w2.x + hA.y * w2.y + hA.z * w2.z + hA.w * w2.w;
            ph1 += hB.x * w2.x + hB.y * w2.y + hB.z * w2.z + hB.w * w2.w;
            pe0 += eA.x * w3.x + eA.y * w3.y + eA.z * w3.z + eA.w * w3.w;
            pe1 += eB.x * w3.x + eB.y * w3.y + eB.z * w3.z + eB.w * w3.w;
        }
        const float bmk = bm[k];
        ms_s[jl][k]     = pa0 + pe0 + deg_s[jl]     * (ph0 + bmk);
        ms_s[jl + 2][k] = pa1 + pe1 + deg_s[jl + 2] * (ph1 + bmk);
    }
    __syncthreads();

    // E: out = h·WuA^T + msum·WuB^T + bu
    {
        float o0 = 0, o1 = 0;
        const float4* __restrict__ wap = (const float4*)WuT4 + k;
        #pragma unroll 4
        for (int q = 0; q < 32; ++q) {
            const float4 wa = wap[q * 128];
            const float4 wb = wap[(32 + q) * 128];
            const float4 hA = *(const float4*)&h_s[jl][4 * q];
            const float4 hB = *(const float4*)&h_s[jl + 2][4 * q];
            const float4 mA = *(const float4*)&ms_s[jl][4 * q];
            const float4 mB = *(const float4*)&ms_s[jl + 2][4 * q];
            o0 += hA.x * wa.x + hA.y * wa.y + hA.z * wa.z + hA.w * wa.w
                + mA.x * wb.x + mA.y * wb.y + mA.z * wb.z + mA.w * wb.w;
            o1 += hB.x * wa.x + hB.y * wa.y + hB.z * wa.z + hB.w * wa.w
                + mB.x * wb.x + mB.y * wb.y + mB.z * wb.z + mB.w * wb.w;
        }
        const float buk = bu[k];
        out[(size_t)(b * NN + jbase + jl) * DD + k]     = o0 + buk;
        out[(size_t)(b * NN + jbase + jl + 2) * DD + k] = o1 + buk;
    }
}

extern "C" void kernel_launch(void* const* d_in, const int* in_sizes, int n_in,
                              void* d_out, int out_size, void* d_ws, size_t ws_size,
                              hipStream_t stream) {
    const float* h   = (const float*)d_in[0];
    const float* adj = (const float*)d_in[1];
    const float* e   = (const float*)d_in[2];
    const float* Wm  = (const float*)d_in[3];
    const float* bm  = (const float*)d_in[4];
    const float* Wu  = (const float*)d_in[5];
    const float* bu  = (const float*)d_in[6];
    float* out  = (float*)d_out;
    float* es   = (float*)d_out;               // alias: fuse block reads only rows it overwrites
    float* WmT4 = (float*)d_ws;                // 384*128 floats
    float* WuT4 = WmT4 + 384 * 128;            // 256*128 floats (320 KB total, proven)

    es_kernel<<<BB * NN, 256, 0, stream>>>(e, adj, es, Wm, Wu, WmT4, WuT4);
    fuse_kernel<<<BB * (NN / 4), 256, 0, stream>>>(h, adj, es, WmT4, bm, WuT4, bu, out);
}